// Round 7
// baseline (136.022 us; speedup 1.0000x reference)
//
#include <hip/hip_runtime.h>

// Mamba selective scan, 3 stream-ordered dispatches.
//   h_t = exp(delta_t * A) * h_{t-1} + delta_t * B_t * x_t
//   y_t = sum_n h_t[n] * C_t[n] + D * x_t
// Round-7 design: 2 ed-channels per thread (float2), halves load/LDS instruction
// count per element and doubles per-thread ILP/MLP. NC=128 chunks, 512 blocks.
// Pass 1: chunk-local scan -> Q (chunk-exit state), Dsum (=sum delta per chunk)
// Pass 2: inter-chunk serial scan -> Hprev (exps chain-independent, grouped-8)
// Pass 3: re-scan seeded with Hprev, fused C-contraction + D*x epilogue -> y

#define LOG2E 1.4426950408889634f

#if __has_builtin(__builtin_amdgcn_exp2f)
#define EXP2F(xx) __builtin_amdgcn_exp2f(xx)
#else
#define EXP2F(xx) exp2f(xx)
#endif

constexpr int BATCH = 2;
constexpr int SEQ   = 2048;
constexpr int ED    = 1024;
constexpr int NS    = 16;

constexpr int NC  = 128;         // chunks
constexpr int CT  = SEQ / NC;    // 16 timesteps/chunk
constexpr int EDG = 256;         // threads per block
constexpr int EPT = 2;           // ed channels per thread
constexpr int EDB = EDG * EPT;   // 512 eds covered per block
constexpr int NEG = ED / EDB;    // 2

// ---------------- pass 1: chunk-local scan ----------------
__global__ __launch_bounds__(EDG, 2) void ssm_pass1(
    const float* __restrict__ x, const float* __restrict__ dl,
    const float* __restrict__ A, const float* __restrict__ B,
    float* __restrict__ Q, float* __restrict__ Dsum)
{
    const int c = blockIdx.x, g = blockIdx.y, b = blockIdx.z;
    const int tid = threadIdx.x;
    const int ed0 = g * EDB + tid * EPT;

    __shared__ alignas(16) float Bs[CT * NS];   // 1 KB
    const long tbase = (long)b * SEQ + (long)c * CT;
    for (int i = tid; i < CT * NS; i += EDG) Bs[i] = B[tbase * NS + i];
    __syncthreads();

    float A2x[NS], A2y[NS];
    {
        const float4* Ax = reinterpret_cast<const float4*>(A + (long)ed0 * NS);
        const float4* Ay = reinterpret_cast<const float4*>(A + (long)(ed0 + 1) * NS);
        #pragma unroll
        for (int k = 0; k < 4; ++k) {
            float4 ax = Ax[k], ay = Ay[k];
            A2x[4*k+0] = ax.x * LOG2E; A2x[4*k+1] = ax.y * LOG2E;
            A2x[4*k+2] = ax.z * LOG2E; A2x[4*k+3] = ax.w * LOG2E;
            A2y[4*k+0] = ay.x * LOG2E; A2y[4*k+1] = ay.y * LOG2E;
            A2y[4*k+2] = ay.z * LOG2E; A2y[4*k+3] = ay.w * LOG2E;
        }
    }

    float hx[NS], hy[NS];
    #pragma unroll
    for (int n = 0; n < NS; ++n) { hx[n] = 0.f; hy[n] = 0.f; }
    float dsx = 0.f, dsy = 0.f;

    const float2* dp = reinterpret_cast<const float2*>(dl + tbase * ED + ed0);
    const float2* xp = reinterpret_cast<const float2*>(x  + tbase * ED + ed0);
    constexpr int RS = ED / 2;   // float2 row stride

    // software pipeline: group-of-4 timesteps, one group of loads ahead
    float2 da[4], xa[4];
    #pragma unroll
    for (int j = 0; j < 4; ++j) { da[j] = dp[(long)j * RS]; xa[j] = xp[(long)j * RS]; }

    for (int tg = 0; tg < CT / 4; ++tg) {
        float2 dn[4], xn[4];
        if (tg < CT / 4 - 1) {
            #pragma unroll
            for (int j = 0; j < 4; ++j) {
                dn[j] = dp[(long)((tg + 1) * 4 + j) * RS];
                xn[j] = xp[(long)((tg + 1) * 4 + j) * RS];
            }
        }
        #pragma unroll
        for (int j = 0; j < 4; ++j) {
            const int t = tg * 4 + j;
            const float2 d2 = da[j], x2 = xa[j];
            dsx += d2.x; dsy += d2.y;
            const float dxx = d2.x * x2.x, dxy = d2.y * x2.y;
            const float4* Bs4 = reinterpret_cast<const float4*>(&Bs[t * NS]);
            #pragma unroll
            for (int k = 0; k < 4; ++k) {
                float4 b4 = Bs4[k];
                hx[4*k+0] = fmaf(EXP2F(d2.x * A2x[4*k+0]), hx[4*k+0], dxx * b4.x);
                hy[4*k+0] = fmaf(EXP2F(d2.y * A2y[4*k+0]), hy[4*k+0], dxy * b4.x);
                hx[4*k+1] = fmaf(EXP2F(d2.x * A2x[4*k+1]), hx[4*k+1], dxx * b4.y);
                hy[4*k+1] = fmaf(EXP2F(d2.y * A2y[4*k+1]), hy[4*k+1], dxy * b4.y);
                hx[4*k+2] = fmaf(EXP2F(d2.x * A2x[4*k+2]), hx[4*k+2], dxx * b4.z);
                hy[4*k+2] = fmaf(EXP2F(d2.y * A2y[4*k+2]), hy[4*k+2], dxy * b4.z);
                hx[4*k+3] = fmaf(EXP2F(d2.x * A2x[4*k+3]), hx[4*k+3], dxx * b4.w);
                hy[4*k+3] = fmaf(EXP2F(d2.y * A2y[4*k+3]), hy[4*k+3], dxy * b4.w);
            }
        }
        #pragma unroll
        for (int j = 0; j < 4; ++j) { da[j] = dn[j]; xa[j] = xn[j]; }
    }

    const long qbase = ((long)(c * BATCH + b) * ED + ed0) * NS;
    float4* Qx = reinterpret_cast<float4*>(Q + qbase);
    float4* Qy = reinterpret_cast<float4*>(Q + qbase + NS);
    #pragma unroll
    for (int k = 0; k < 4; ++k) {
        Qx[k] = make_float4(hx[4*k+0], hx[4*k+1], hx[4*k+2], hx[4*k+3]);
        Qy[k] = make_float4(hy[4*k+0], hy[4*k+1], hy[4*k+2], hy[4*k+3]);
    }
    float2* Dp = reinterpret_cast<float2*>(Dsum + (long)(c * BATCH + b) * ED + ed0);
    *Dp = make_float2(dsx, dsy);
}

// ---------------- pass 2: inter-chunk scan ----------------
// One thread per (b, ed, n): 32768 items = 256 blocks x 128 threads.
// P factors are chain-independent -> grouped-8 prefetch + 8 exps, then 8 fmas.
__global__ __launch_bounds__(128) void ssm_pass2(
    const float* __restrict__ A, const float* __restrict__ Q,
    const float* __restrict__ Dsum, float* __restrict__ Hprev)
{
    const int idx = blockIdx.x * 128 + threadIdx.x;
    const int n  = idx & (NS - 1);
    const int ed = (idx >> 4) & (ED - 1);
    const int b  = idx >> 14;

    const float a2 = A[(long)ed * NS + n] * LOG2E;
    const long strideQ = (long)BATCH * ED * NS;
    const long strideD = (long)BATCH * ED;
    const long o0 = ((long)b * ED + ed) * NS + n;
    const long d0 = (long)b * ED + ed;

    float h = 0.f;
    float qs[8], ds[8];
    #pragma unroll
    for (int j = 0; j < 8; ++j) {
        qs[j] = Q[o0 + (long)j * strideQ];
        ds[j] = Dsum[d0 + (long)j * strideD];
    }
    for (int gi = 0; gi < NC / 8; ++gi) {
        float qn[8], dn[8];
        if (gi < NC / 8 - 1) {
            #pragma unroll
            for (int j = 0; j < 8; ++j) {
                qn[j] = Q[o0 + (long)((gi + 1) * 8 + j) * strideQ];
                dn[j] = Dsum[d0 + (long)((gi + 1) * 8 + j) * strideD];
            }
        }
        float ps[8];
        #pragma unroll
        for (int j = 0; j < 8; ++j) ps[j] = EXP2F(a2 * ds[j]);
        #pragma unroll
        for (int j = 0; j < 8; ++j) {
            Hprev[o0 + (long)(gi * 8 + j) * strideQ] = h;   // state BEFORE chunk
            h = fmaf(ps[j], h, qs[j]);
        }
        #pragma unroll
        for (int j = 0; j < 8; ++j) { qs[j] = qn[j]; ds[j] = dn[j]; }
    }
}

// ---------------- pass 3: seeded re-scan + fused epilogue ----------------
__global__ __launch_bounds__(EDG, 2) void ssm_pass3(
    const float* __restrict__ x, const float* __restrict__ dl,
    const float* __restrict__ A, const float* __restrict__ B,
    const float* __restrict__ C, const float* __restrict__ Dv,
    const float* __restrict__ Hprev, float* __restrict__ y)
{
    const int c = blockIdx.x, g = blockIdx.y, b = blockIdx.z;
    const int tid = threadIdx.x;
    const int ed0 = g * EDB + tid * EPT;

    __shared__ alignas(16) float Bs[CT * NS];
    __shared__ alignas(16) float Cs[CT * NS];
    const long tbase = (long)b * SEQ + (long)c * CT;
    for (int i = tid; i < CT * NS; i += EDG) {
        Bs[i] = B[tbase * NS + i];
        Cs[i] = C[tbase * NS + i];
    }
    __syncthreads();

    float A2x[NS], A2y[NS];
    {
        const float4* Ax = reinterpret_cast<const float4*>(A + (long)ed0 * NS);
        const float4* Ay = reinterpret_cast<const float4*>(A + (long)(ed0 + 1) * NS);
        #pragma unroll
        for (int k = 0; k < 4; ++k) {
            float4 ax = Ax[k], ay = Ay[k];
            A2x[4*k+0] = ax.x * LOG2E; A2x[4*k+1] = ax.y * LOG2E;
            A2x[4*k+2] = ax.z * LOG2E; A2x[4*k+3] = ax.w * LOG2E;
            A2y[4*k+0] = ay.x * LOG2E; A2y[4*k+1] = ay.y * LOG2E;
            A2y[4*k+2] = ay.z * LOG2E; A2y[4*k+3] = ay.w * LOG2E;
        }
    }

    float hx[NS], hy[NS];
    {
        const long qbase = ((long)(c * BATCH + b) * ED + ed0) * NS;
        const float4* Hx = reinterpret_cast<const float4*>(Hprev + qbase);
        const float4* Hy = reinterpret_cast<const float4*>(Hprev + qbase + NS);
        #pragma unroll
        for (int k = 0; k < 4; ++k) {
            float4 h4x = Hx[k], h4y = Hy[k];
            hx[4*k+0] = h4x.x; hx[4*k+1] = h4x.y; hx[4*k+2] = h4x.z; hx[4*k+3] = h4x.w;
            hy[4*k+0] = h4y.x; hy[4*k+1] = h4y.y; hy[4*k+2] = h4y.z; hy[4*k+3] = h4y.w;
        }
    }
    const float2 dvec = *reinterpret_cast<const float2*>(Dv + ed0);

    const float2* dp = reinterpret_cast<const float2*>(dl + tbase * ED + ed0);
    const float2* xp = reinterpret_cast<const float2*>(x  + tbase * ED + ed0);
    float2* yp = reinterpret_cast<float2*>(y + tbase * ED + ed0);
    constexpr int RS = ED / 2;

    float2 da[4], xa[4];
    #pragma unroll
    for (int j = 0; j < 4; ++j) { da[j] = dp[(long)j * RS]; xa[j] = xp[(long)j * RS]; }

    for (int tg = 0; tg < CT / 4; ++tg) {
        float2 dn[4], xn[4];
        if (tg < CT / 4 - 1) {
            #pragma unroll
            for (int j = 0; j < 4; ++j) {
                dn[j] = dp[(long)((tg + 1) * 4 + j) * RS];
                xn[j] = xp[(long)((tg + 1) * 4 + j) * RS];
            }
        }
        #pragma unroll
        for (int j = 0; j < 4; ++j) {
            const int t = tg * 4 + j;
            const float2 d2 = da[j], x2 = xa[j];
            const float dxx = d2.x * x2.x, dxy = d2.y * x2.y;
            float accx = dvec.x * x2.x, accy = dvec.y * x2.y;
            const float4* Bs4 = reinterpret_cast<const float4*>(&Bs[t * NS]);
            const float4* Cs4 = reinterpret_cast<const float4*>(&Cs[t * NS]);
            #pragma unroll
            for (int k = 0; k < 4; ++k) {
                float4 b4 = Bs4[k];
                float4 c4 = Cs4[k];
                hx[4*k+0] = fmaf(EXP2F(d2.x * A2x[4*k+0]), hx[4*k+0], dxx * b4.x);
                hy[4*k+0] = fmaf(EXP2F(d2.y * A2y[4*k+0]), hy[4*k+0], dxy * b4.x);
                accx = fmaf(hx[4*k+0], c4.x, accx);
                accy = fmaf(hy[4*k+0], c4.x, accy);
                hx[4*k+1] = fmaf(EXP2F(d2.x * A2x[4*k+1]), hx[4*k+1], dxx * b4.y);
                hy[4*k+1] = fmaf(EXP2F(d2.y * A2y[4*k+1]), hy[4*k+1], dxy * b4.y);
                accx = fmaf(hx[4*k+1], c4.y, accx);
                accy = fmaf(hy[4*k+1], c4.y, accy);
                hx[4*k+2] = fmaf(EXP2F(d2.x * A2x[4*k+2]), hx[4*k+2], dxx * b4.z);
                hy[4*k+2] = fmaf(EXP2F(d2.y * A2y[4*k+2]), hy[4*k+2], dxy * b4.z);
                accx = fmaf(hx[4*k+2], c4.z, accx);
                accy = fmaf(hy[4*k+2], c4.z, accy);
                hx[4*k+3] = fmaf(EXP2F(d2.x * A2x[4*k+3]), hx[4*k+3], dxx * b4.w);
                hy[4*k+3] = fmaf(EXP2F(d2.y * A2y[4*k+3]), hy[4*k+3], dxy * b4.w);
                accx = fmaf(hx[4*k+3], c4.w, accx);
                accy = fmaf(hy[4*k+3], c4.w, accy);
            }
            yp[(long)t * RS] = make_float2(accx, accy);
        }
        #pragma unroll
        for (int j = 0; j < 4; ++j) { da[j] = dn[j]; xa[j] = xn[j]; }
    }
}

// ---------------- fallback (tiny workspace): fully sequential ----------------
__global__ __launch_bounds__(EDG) void ssm_fallback(
    const float* __restrict__ x, const float* __restrict__ dl,
    const float* __restrict__ A, const float* __restrict__ B,
    const float* __restrict__ C, const float* __restrict__ Dv,
    float* __restrict__ y)
{
    const int g = blockIdx.x, b = blockIdx.y;
    const int ed = g * EDG + threadIdx.x;

    float A2[NS];
    {
        const float4* Ap = reinterpret_cast<const float4*>(A + (long)ed * NS);
        #pragma unroll
        for (int k = 0; k < 4; ++k) {
            float4 a4 = Ap[k];
            A2[4*k+0] = a4.x * LOG2E; A2[4*k+1] = a4.y * LOG2E;
            A2[4*k+2] = a4.z * LOG2E; A2[4*k+3] = a4.w * LOG2E;
        }
    }
    float h[NS];
    #pragma unroll
    for (int n = 0; n < NS; ++n) h[n] = 0.f;
    const float dvec = Dv[ed];

    for (int t = 0; t < SEQ; ++t) {
        const long tb = (long)b * SEQ + t;
        float dlt = dl[tb * ED + ed];
        float xv  = x[tb * ED + ed];
        float dx = dlt * xv;
        float acc = dvec * xv;
        const float4* Bp = reinterpret_cast<const float4*>(B + tb * NS);
        const float4* Cp = reinterpret_cast<const float4*>(C + tb * NS);
        #pragma unroll
        for (int k = 0; k < 4; ++k) {
            float4 b4 = Bp[k];
            float4 c4 = Cp[k];
            h[4*k+0] = fmaf(EXP2F(dlt * A2[4*k+0]), h[4*k+0], dx * b4.x);
            acc = fmaf(h[4*k+0], c4.x, acc);
            h[4*k+1] = fmaf(EXP2F(dlt * A2[4*k+1]), h[4*k+1], dx * b4.y);
            acc = fmaf(h[4*k+1], c4.y, acc);
            h[4*k+2] = fmaf(EXP2F(dlt * A2[4*k+2]), h[4*k+2], dx * b4.z);
            acc = fmaf(h[4*k+2], c4.z, acc);
            h[4*k+3] = fmaf(EXP2F(dlt * A2[4*k+3]), h[4*k+3], dx * b4.w);
            acc = fmaf(h[4*k+3], c4.w, acc);
        }
        y[tb * ED + ed] = acc;
    }
}

extern "C" void kernel_launch(void* const* d_in, const int* in_sizes, int n_in,
                              void* d_out, int out_size, void* d_ws, size_t ws_size,
                              hipStream_t stream) {
    const float* x  = (const float*)d_in[0];
    const float* dl = (const float*)d_in[1];
    const float* A  = (const float*)d_in[2];
    const float* B  = (const float*)d_in[3];
    const float* C  = (const float*)d_in[4];
    const float* Dv = (const float*)d_in[5];
    float* y = (float*)d_out;

    const size_t qElems = (size_t)NC * BATCH * ED * NS;   // 4M floats
    const size_t dElems = (size_t)NC * BATCH * ED;        // 256K floats
    const size_t need = (2 * qElems + dElems) * sizeof(float);  // ~33.5 MB

    if (ws_size >= need) {
        float* Q     = (float*)d_ws;
        float* Hprev = Q + qElems;
        float* Dsum  = Hprev + qElems;
        ssm_pass1<<<dim3(NC, NEG, BATCH), EDG, 0, stream>>>(x, dl, A, B, Q, Dsum);
        ssm_pass2<<<(BATCH * ED * NS) / 128, 128, 0, stream>>>(A, Q, Dsum, Hprev);
        ssm_pass3<<<dim3(NC, NEG, BATCH), EDG, 0, stream>>>(x, dl, A, B, C, Dv, Hprev, y);
    } else {
        ssm_fallback<<<dim3(NEG, BATCH), EDG, 0, stream>>>(x, dl, A, B, C, Dv, y);
    }
}

// Round 8
// 118.061 us; speedup vs baseline: 1.1521x; 1.1521x over previous
//
#include <hip/hip_runtime.h>

// Mamba selective scan, 3 stream-ordered dispatches. NC=64 (proven best, R5).
//   h_t = exp(delta_t * A) * h_{t-1} + delta_t * B_t * x_t
//   y_t = sum_n h_t[n] * C_t[n] + D * x_t
// Round-8 change vs R5: full-chunk register staging of x/delta (all 64 loads
// issued before any consume -> one latency exposure per chunk, not per 4-step
// group; the R5 rotating prefetch drained vmcnt each group).
// Pass 1: chunk-local scan -> Q (exit state), Dsum (sum of delta per chunk)
// Pass 2: inter-chunk serial scan -> Hprev (exps chain-independent, grouped-8)
// Pass 3: re-scan seeded with Hprev, fused C-contraction + D*x epilogue -> y

#define LOG2E 1.4426950408889634f

#if __has_builtin(__builtin_amdgcn_exp2f)
#define EXP2F(xx) __builtin_amdgcn_exp2f(xx)
#else
#define EXP2F(xx) exp2f(xx)
#endif

constexpr int BATCH = 2;
constexpr int SEQ   = 2048;
constexpr int ED    = 1024;
constexpr int NS    = 16;

constexpr int NC  = 64;          // chunks
constexpr int CT  = SEQ / NC;    // 32 timesteps/chunk
constexpr int EDG = 256;         // threads per block (1 ed/thread)
constexpr int NEG = ED / EDG;    // 4
constexpr int HT  = CT / 2;      // half-chunk = 16 timesteps

// ---------------- pass 1: chunk-local scan ----------------
__global__ __launch_bounds__(EDG, 2) void ssm_pass1(
    const float* __restrict__ x, const float* __restrict__ dl,
    const float* __restrict__ A, const float* __restrict__ B,
    float* __restrict__ Q, float* __restrict__ Dsum)
{
    const int c = blockIdx.x, g = blockIdx.y, b = blockIdx.z;
    const int tid = threadIdx.x;
    const int ed = g * EDG + tid;

    __shared__ alignas(16) float Bs[CT * NS];   // 2 KB
    const long tbase = (long)b * SEQ + (long)c * CT;
    for (int i = tid; i < CT * NS; i += EDG) Bs[i] = B[tbase * NS + i];
    __syncthreads();

    const float* dp = dl + tbase * ED + ed;
    const float* xp = x  + tbase * ED + ed;

    // stage the whole chunk: all 64 loads issued up-front (static indices)
    float da[HT], xa[HT], db[HT], xb[HT];
    #pragma unroll
    for (int j = 0; j < HT; ++j) { da[j] = dp[(long)j * ED];        xa[j] = xp[(long)j * ED]; }
    #pragma unroll
    for (int j = 0; j < HT; ++j) { db[j] = dp[(long)(HT + j) * ED]; xb[j] = xp[(long)(HT + j) * ED]; }

    float A2[NS];
    {
        const float4* Ap = reinterpret_cast<const float4*>(A + (long)ed * NS);
        #pragma unroll
        for (int k = 0; k < 4; ++k) {
            float4 a4 = Ap[k];
            A2[4*k+0] = a4.x * LOG2E; A2[4*k+1] = a4.y * LOG2E;
            A2[4*k+2] = a4.z * LOG2E; A2[4*k+3] = a4.w * LOG2E;
        }
    }

    float h[NS];
    #pragma unroll
    for (int n = 0; n < NS; ++n) h[n] = 0.f;
    float dsum = 0.f;

    #pragma unroll
    for (int t = 0; t < CT; ++t) {
        const float dlt = (t < HT) ? da[t] : db[t - HT];
        const float xv  = (t < HT) ? xa[t] : xb[t - HT];
        dsum += dlt;
        const float dx = dlt * xv;
        const float4* Bs4 = reinterpret_cast<const float4*>(&Bs[t * NS]);
        #pragma unroll
        for (int k = 0; k < 4; ++k) {
            float4 b4 = Bs4[k];
            h[4*k+0] = fmaf(EXP2F(dlt * A2[4*k+0]), h[4*k+0], dx * b4.x);
            h[4*k+1] = fmaf(EXP2F(dlt * A2[4*k+1]), h[4*k+1], dx * b4.y);
            h[4*k+2] = fmaf(EXP2F(dlt * A2[4*k+2]), h[4*k+2], dx * b4.z);
            h[4*k+3] = fmaf(EXP2F(dlt * A2[4*k+3]), h[4*k+3], dx * b4.w);
        }
    }

    const long qo = ((long)(c * BATCH + b) * ED + ed) * NS;
    float4* Qp = reinterpret_cast<float4*>(Q + qo);
    #pragma unroll
    for (int k = 0; k < 4; ++k)
        Qp[k] = make_float4(h[4*k+0], h[4*k+1], h[4*k+2], h[4*k+3]);
    Dsum[(long)(c * BATCH + b) * ED + ed] = dsum;
}

// ---------------- pass 2: inter-chunk scan ----------------
// One thread per (b, ed, n): 32768 items = 256 blocks x 128 threads.
// P factors are chain-independent -> grouped-8 prefetch + 8 exps, then 8 fmas.
__global__ __launch_bounds__(128) void ssm_pass2(
    const float* __restrict__ A, const float* __restrict__ Q,
    const float* __restrict__ Dsum, float* __restrict__ Hprev)
{
    const int idx = blockIdx.x * 128 + threadIdx.x;
    const int n  = idx & (NS - 1);
    const int ed = (idx >> 4) & (ED - 1);
    const int b  = idx >> 14;

    const float a2 = A[(long)ed * NS + n] * LOG2E;
    const long strideQ = (long)BATCH * ED * NS;
    const long strideD = (long)BATCH * ED;
    const long o0 = ((long)b * ED + ed) * NS + n;
    const long d0 = (long)b * ED + ed;

    float h = 0.f;
    float qs[8], ds[8];
    #pragma unroll
    for (int j = 0; j < 8; ++j) {
        qs[j] = Q[o0 + (long)j * strideQ];
        ds[j] = Dsum[d0 + (long)j * strideD];
    }
    for (int gi = 0; gi < NC / 8; ++gi) {
        float qn[8], dn[8];
        if (gi < NC / 8 - 1) {
            #pragma unroll
            for (int j = 0; j < 8; ++j) {
                qn[j] = Q[o0 + (long)((gi + 1) * 8 + j) * strideQ];
                dn[j] = Dsum[d0 + (long)((gi + 1) * 8 + j) * strideD];
            }
        }
        float ps[8];
        #pragma unroll
        for (int j = 0; j < 8; ++j) ps[j] = EXP2F(a2 * ds[j]);
        #pragma unroll
        for (int j = 0; j < 8; ++j) {
            Hprev[o0 + (long)(gi * 8 + j) * strideQ] = h;   // state BEFORE chunk
            h = fmaf(ps[j], h, qs[j]);
        }
        #pragma unroll
        for (int j = 0; j < 8; ++j) { qs[j] = qn[j]; ds[j] = dn[j]; }
    }
}

// ---------------- pass 3: seeded re-scan + fused epilogue ----------------
__global__ __launch_bounds__(EDG, 2) void ssm_pass3(
    const float* __restrict__ x, const float* __restrict__ dl,
    const float* __restrict__ A, const float* __restrict__ B,
    const float* __restrict__ C, const float* __restrict__ Dv,
    const float* __restrict__ Hprev, float* __restrict__ y)
{
    const int c = blockIdx.x, g = blockIdx.y, b = blockIdx.z;
    const int tid = threadIdx.x;
    const int ed = g * EDG + tid;

    __shared__ alignas(16) float Bs[CT * NS];
    __shared__ alignas(16) float Cs[CT * NS];
    const long tbase = (long)b * SEQ + (long)c * CT;
    for (int i = tid; i < CT * NS; i += EDG) {
        Bs[i] = B[tbase * NS + i];
        Cs[i] = C[tbase * NS + i];
    }
    __syncthreads();

    const float* dp = dl + tbase * ED + ed;
    const float* xp = x  + tbase * ED + ed;
    float* yp = y + tbase * ED + ed;

    // stage the whole chunk up-front
    float da[HT], xa[HT], db[HT], xb[HT];
    #pragma unroll
    for (int j = 0; j < HT; ++j) { da[j] = dp[(long)j * ED];        xa[j] = xp[(long)j * ED]; }
    #pragma unroll
    for (int j = 0; j < HT; ++j) { db[j] = dp[(long)(HT + j) * ED]; xb[j] = xp[(long)(HT + j) * ED]; }

    float A2[NS];
    {
        const float4* Ap = reinterpret_cast<const float4*>(A + (long)ed * NS);
        #pragma unroll
        for (int k = 0; k < 4; ++k) {
            float4 a4 = Ap[k];
            A2[4*k+0] = a4.x * LOG2E; A2[4*k+1] = a4.y * LOG2E;
            A2[4*k+2] = a4.z * LOG2E; A2[4*k+3] = a4.w * LOG2E;
        }
    }

    float h[NS];
    {
        const long qo = ((long)(c * BATCH + b) * ED + ed) * NS;
        const float4* Hp = reinterpret_cast<const float4*>(Hprev + qo);
        #pragma unroll
        for (int k = 0; k < 4; ++k) {
            float4 h4 = Hp[k];
            h[4*k+0] = h4.x; h[4*k+1] = h4.y; h[4*k+2] = h4.z; h[4*k+3] = h4.w;
        }
    }
    const float dvec = Dv[ed];

    #pragma unroll
    for (int t = 0; t < CT; ++t) {
        const float dlt = (t < HT) ? da[t] : db[t - HT];
        const float xv  = (t < HT) ? xa[t] : xb[t - HT];
        const float dx = dlt * xv;
        float acc = dvec * xv;
        const float4* Bs4 = reinterpret_cast<const float4*>(&Bs[t * NS]);
        const float4* Cs4 = reinterpret_cast<const float4*>(&Cs[t * NS]);
        #pragma unroll
        for (int k = 0; k < 4; ++k) {
            float4 b4 = Bs4[k];
            float4 c4 = Cs4[k];
            h[4*k+0] = fmaf(EXP2F(dlt * A2[4*k+0]), h[4*k+0], dx * b4.x);
            acc = fmaf(h[4*k+0], c4.x, acc);
            h[4*k+1] = fmaf(EXP2F(dlt * A2[4*k+1]), h[4*k+1], dx * b4.y);
            acc = fmaf(h[4*k+1], c4.y, acc);
            h[4*k+2] = fmaf(EXP2F(dlt * A2[4*k+2]), h[4*k+2], dx * b4.z);
            acc = fmaf(h[4*k+2], c4.z, acc);
            h[4*k+3] = fmaf(EXP2F(dlt * A2[4*k+3]), h[4*k+3], dx * b4.w);
            acc = fmaf(h[4*k+3], c4.w, acc);
        }
        yp[(long)t * ED] = acc;
    }
}

// ---------------- fallback (tiny workspace): fully sequential ----------------
__global__ __launch_bounds__(EDG) void ssm_fallback(
    const float* __restrict__ x, const float* __restrict__ dl,
    const float* __restrict__ A, const float* __restrict__ B,
    const float* __restrict__ C, const float* __restrict__ Dv,
    float* __restrict__ y)
{
    const int g = blockIdx.x, b = blockIdx.y;
    const int ed = g * EDG + threadIdx.x;

    float A2[NS];
    {
        const float4* Ap = reinterpret_cast<const float4*>(A + (long)ed * NS);
        #pragma unroll
        for (int k = 0; k < 4; ++k) {
            float4 a4 = Ap[k];
            A2[4*k+0] = a4.x * LOG2E; A2[4*k+1] = a4.y * LOG2E;
            A2[4*k+2] = a4.z * LOG2E; A2[4*k+3] = a4.w * LOG2E;
        }
    }
    float h[NS];
    #pragma unroll
    for (int n = 0; n < NS; ++n) h[n] = 0.f;
    const float dvec = Dv[ed];

    for (int t = 0; t < SEQ; ++t) {
        const long tb = (long)b * SEQ + t;
        float dlt = dl[tb * ED + ed];
        float xv  = x[tb * ED + ed];
        float dx = dlt * xv;
        float acc = dvec * xv;
        const float4* Bp = reinterpret_cast<const float4*>(B + tb * NS);
        const float4* Cp = reinterpret_cast<const float4*>(C + tb * NS);
        #pragma unroll
        for (int k = 0; k < 4; ++k) {
            float4 b4 = Bp[k];
            float4 c4 = Cp[k];
            h[4*k+0] = fmaf(EXP2F(dlt * A2[4*k+0]), h[4*k+0], dx * b4.x);
            acc = fmaf(h[4*k+0], c4.x, acc);
            h[4*k+1] = fmaf(EXP2F(dlt * A2[4*k+1]), h[4*k+1], dx * b4.y);
            acc = fmaf(h[4*k+1], c4.y, acc);
            h[4*k+2] = fmaf(EXP2F(dlt * A2[4*k+2]), h[4*k+2], dx * b4.z);
            acc = fmaf(h[4*k+2], c4.z, acc);
            h[4*k+3] = fmaf(EXP2F(dlt * A2[4*k+3]), h[4*k+3], dx * b4.w);
            acc = fmaf(h[4*k+3], c4.w, acc);
        }
        y[tb * ED + ed] = acc;
    }
}

extern "C" void kernel_launch(void* const* d_in, const int* in_sizes, int n_in,
                              void* d_out, int out_size, void* d_ws, size_t ws_size,
                              hipStream_t stream) {
    const float* x  = (const float*)d_in[0];
    const float* dl = (const float*)d_in[1];
    const float* A  = (const float*)d_in[2];
    const float* B  = (const float*)d_in[3];
    const float* C  = (const float*)d_in[4];
    const float* Dv = (const float*)d_in[5];
    float* y = (float*)d_out;

    const size_t qElems = (size_t)NC * BATCH * ED * NS;   // 2M floats
    const size_t dElems = (size_t)NC * BATCH * ED;        // 128K floats
    const size_t need = (2 * qElems + dElems) * sizeof(float);  // ~16.5 MB

    if (ws_size >= need) {
        float* Q     = (float*)d_ws;
        float* Hprev = Q + qElems;
        float* Dsum  = Hprev + qElems;
        ssm_pass1<<<dim3(NC, NEG, BATCH), EDG, 0, stream>>>(x, dl, A, B, Q, Dsum);
        ssm_pass2<<<(BATCH * ED * NS) / 128, 128, 0, stream>>>(A, Q, Dsum, Hprev);
        ssm_pass3<<<dim3(NC, NEG, BATCH), EDG, 0, stream>>>(x, dl, A, B, C, Dv, Hprev, y);
    } else {
        ssm_fallback<<<dim3(NEG, BATCH), EDG, 0, stream>>>(x, dl, A, B, C, Dv, y);
    }
}

// Round 9
// 113.513 us; speedup vs baseline: 1.1983x; 1.0401x over previous
//
#include <hip/hip_runtime.h>

// Mamba selective scan, 3 stream-ordered dispatches. EXACT round-5 structure
// (best measured: 114.3us) + nontemporal y stores.
// Variant scorecard: R5 rotating-prefetch NC=64: 114.3 | R6 NC=128: 120.4 |
// R7 float2/EPT2: 136.0 | R8 full-chunk stage: 118.1 -> scheduling-insensitive;
// residual is fixed harness tax (~50us: 256MiB poison fill 43us + restores)
// + 3 forced dispatches (grid barrier costs ~300us on MI355X, R3).
//   h_t = exp(delta_t * A) * h_{t-1} + delta_t * B_t * x_t
//   y_t = sum_n h_t[n] * C_t[n] + D * x_t
// Pass 1: chunk-local scan -> Q (exit state), Dsum (sum delta per chunk)
// Pass 2: inter-chunk serial scan -> Hprev (exps chain-independent, grouped-8)
// Pass 3: re-scan seeded with Hprev, fused C-contraction + D*x epilogue -> y

#define LOG2E 1.4426950408889634f

#if __has_builtin(__builtin_amdgcn_exp2f)
#define EXP2F(xx) __builtin_amdgcn_exp2f(xx)
#else
#define EXP2F(xx) exp2f(xx)
#endif

constexpr int BATCH = 2;
constexpr int SEQ   = 2048;
constexpr int ED    = 1024;
constexpr int NS    = 16;

constexpr int NC  = 64;          // chunks
constexpr int CT  = SEQ / NC;    // 32 timesteps/chunk
constexpr int EDG = 256;         // ed channels per block
constexpr int NEG = ED / EDG;    // 4

// ---------------- pass 1: chunk-local scan ----------------
__global__ __launch_bounds__(EDG, 2) void ssm_pass1(
    const float* __restrict__ x, const float* __restrict__ dl,
    const float* __restrict__ A, const float* __restrict__ B,
    float* __restrict__ Q, float* __restrict__ Dsum)
{
    const int c = blockIdx.x, g = blockIdx.y, b = blockIdx.z;
    const int tid = threadIdx.x;
    const int ed = g * EDG + tid;

    __shared__ alignas(16) float Bs[CT * NS];   // 2 KB
    const long tbase = (long)b * SEQ + (long)c * CT;
    for (int i = tid; i < CT * NS; i += EDG) Bs[i] = B[tbase * NS + i];
    __syncthreads();

    float A2[NS];
    {
        const float4* Ap = reinterpret_cast<const float4*>(A + (long)ed * NS);
        #pragma unroll
        for (int k = 0; k < 4; ++k) {
            float4 a4 = Ap[k];
            A2[4*k+0] = a4.x * LOG2E; A2[4*k+1] = a4.y * LOG2E;
            A2[4*k+2] = a4.z * LOG2E; A2[4*k+3] = a4.w * LOG2E;
        }
    }

    float h[NS];
    #pragma unroll
    for (int n = 0; n < NS; ++n) h[n] = 0.f;
    float dsum = 0.f;

    const float* dp = dl + tbase * ED + ed;
    const float* xp = x  + tbase * ED + ed;

    // software pipeline: group-of-4, one group of loads ahead (8 loads in flight)
    float da[4], xa[4];
    #pragma unroll
    for (int j = 0; j < 4; ++j) { da[j] = dp[(long)j * ED]; xa[j] = xp[(long)j * ED]; }

    for (int tg = 0; tg < CT / 4; ++tg) {
        float dn[4], xn[4];
        if (tg < CT / 4 - 1) {
            #pragma unroll
            for (int j = 0; j < 4; ++j) {
                dn[j] = dp[(long)((tg + 1) * 4 + j) * ED];
                xn[j] = xp[(long)((tg + 1) * 4 + j) * ED];
            }
        }
        #pragma unroll
        for (int j = 0; j < 4; ++j) {
            const int t = tg * 4 + j;
            float dlt = da[j], xv = xa[j];
            dsum += dlt;
            float dx = dlt * xv;
            const float4* Bs4 = reinterpret_cast<const float4*>(&Bs[t * NS]);
            #pragma unroll
            for (int k = 0; k < 4; ++k) {
                float4 b4 = Bs4[k];
                h[4*k+0] = fmaf(EXP2F(dlt * A2[4*k+0]), h[4*k+0], dx * b4.x);
                h[4*k+1] = fmaf(EXP2F(dlt * A2[4*k+1]), h[4*k+1], dx * b4.y);
                h[4*k+2] = fmaf(EXP2F(dlt * A2[4*k+2]), h[4*k+2], dx * b4.z);
                h[4*k+3] = fmaf(EXP2F(dlt * A2[4*k+3]), h[4*k+3], dx * b4.w);
            }
        }
        #pragma unroll
        for (int j = 0; j < 4; ++j) { da[j] = dn[j]; xa[j] = xn[j]; }
    }

    const long qo = ((long)(c * BATCH + b) * ED + ed) * NS;
    float4* Qp = reinterpret_cast<float4*>(Q + qo);
    #pragma unroll
    for (int k = 0; k < 4; ++k)
        Qp[k] = make_float4(h[4*k+0], h[4*k+1], h[4*k+2], h[4*k+3]);
    Dsum[(long)(c * BATCH + b) * ED + ed] = dsum;
}

// ---------------- pass 2: inter-chunk scan ----------------
// One thread per (b, ed, n): 32768 items = 256 blocks x 128 threads.
// P factors are chain-independent -> grouped-8 prefetch + 8 exps, then 8 fmas.
__global__ __launch_bounds__(128) void ssm_pass2(
    const float* __restrict__ A, const float* __restrict__ Q,
    const float* __restrict__ Dsum, float* __restrict__ Hprev)
{
    const int idx = blockIdx.x * 128 + threadIdx.x;
    const int n  = idx & (NS - 1);
    const int ed = (idx >> 4) & (ED - 1);
    const int b  = idx >> 14;

    const float a2 = A[(long)ed * NS + n] * LOG2E;
    const long strideQ = (long)BATCH * ED * NS;
    const long strideD = (long)BATCH * ED;
    const long o0 = ((long)b * ED + ed) * NS + n;
    const long d0 = (long)b * ED + ed;

    float h = 0.f;
    float qs[8], ds[8];
    #pragma unroll
    for (int j = 0; j < 8; ++j) {
        qs[j] = Q[o0 + (long)j * strideQ];
        ds[j] = Dsum[d0 + (long)j * strideD];
    }
    for (int gi = 0; gi < NC / 8; ++gi) {
        float qn[8], dn[8];
        if (gi < NC / 8 - 1) {
            #pragma unroll
            for (int j = 0; j < 8; ++j) {
                qn[j] = Q[o0 + (long)((gi + 1) * 8 + j) * strideQ];
                dn[j] = Dsum[d0 + (long)((gi + 1) * 8 + j) * strideD];
            }
        }
        float ps[8];
        #pragma unroll
        for (int j = 0; j < 8; ++j) ps[j] = EXP2F(a2 * ds[j]);
        #pragma unroll
        for (int j = 0; j < 8; ++j) {
            Hprev[o0 + (long)(gi * 8 + j) * strideQ] = h;   // state BEFORE chunk
            h = fmaf(ps[j], h, qs[j]);
        }
        #pragma unroll
        for (int j = 0; j < 8; ++j) { qs[j] = qn[j]; ds[j] = dn[j]; }
    }
}

// ---------------- pass 3: seeded re-scan + fused epilogue ----------------
__global__ __launch_bounds__(EDG, 2) void ssm_pass3(
    const float* __restrict__ x, const float* __restrict__ dl,
    const float* __restrict__ A, const float* __restrict__ B,
    const float* __restrict__ C, const float* __restrict__ Dv,
    const float* __restrict__ Hprev, float* __restrict__ y)
{
    const int c = blockIdx.x, g = blockIdx.y, b = blockIdx.z;
    const int tid = threadIdx.x;
    const int ed = g * EDG + tid;

    __shared__ alignas(16) float Bs[CT * NS];
    __shared__ alignas(16) float Cs[CT * NS];
    const long tbase = (long)b * SEQ + (long)c * CT;
    for (int i = tid; i < CT * NS; i += EDG) {
        Bs[i] = B[tbase * NS + i];
        Cs[i] = C[tbase * NS + i];
    }
    __syncthreads();

    float A2[NS];
    {
        const float4* Ap = reinterpret_cast<const float4*>(A + (long)ed * NS);
        #pragma unroll
        for (int k = 0; k < 4; ++k) {
            float4 a4 = Ap[k];
            A2[4*k+0] = a4.x * LOG2E; A2[4*k+1] = a4.y * LOG2E;
            A2[4*k+2] = a4.z * LOG2E; A2[4*k+3] = a4.w * LOG2E;
        }
    }

    float h[NS];
    {
        const long qo = ((long)(c * BATCH + b) * ED + ed) * NS;
        const float4* Hp = reinterpret_cast<const float4*>(Hprev + qo);
        #pragma unroll
        for (int k = 0; k < 4; ++k) {
            float4 h4 = Hp[k];
            h[4*k+0] = h4.x; h[4*k+1] = h4.y; h[4*k+2] = h4.z; h[4*k+3] = h4.w;
        }
    }
    const float dvec = Dv[ed];

    const float* dp = dl + tbase * ED + ed;
    const float* xp = x  + tbase * ED + ed;
    float* yp = y + tbase * ED + ed;

    float da[4], xa[4];
    #pragma unroll
    for (int j = 0; j < 4; ++j) { da[j] = dp[(long)j * ED]; xa[j] = xp[(long)j * ED]; }

    for (int tg = 0; tg < CT / 4; ++tg) {
        float dn[4], xn[4];
        if (tg < CT / 4 - 1) {
            #pragma unroll
            for (int j = 0; j < 4; ++j) {
                dn[j] = dp[(long)((tg + 1) * 4 + j) * ED];
                xn[j] = xp[(long)((tg + 1) * 4 + j) * ED];
            }
        }
        #pragma unroll
        for (int j = 0; j < 4; ++j) {
            const int t = tg * 4 + j;
            float dlt = da[j], xv = xa[j];
            float dx = dlt * xv;
            float acc = dvec * xv;
            const float4* Bs4 = reinterpret_cast<const float4*>(&Bs[t * NS]);
            const float4* Cs4 = reinterpret_cast<const float4*>(&Cs[t * NS]);
            #pragma unroll
            for (int k = 0; k < 4; ++k) {
                float4 b4 = Bs4[k];
                float4 c4 = Cs4[k];
                h[4*k+0] = fmaf(EXP2F(dlt * A2[4*k+0]), h[4*k+0], dx * b4.x);
                acc = fmaf(h[4*k+0], c4.x, acc);
                h[4*k+1] = fmaf(EXP2F(dlt * A2[4*k+1]), h[4*k+1], dx * b4.y);
                acc = fmaf(h[4*k+1], c4.y, acc);
                h[4*k+2] = fmaf(EXP2F(dlt * A2[4*k+2]), h[4*k+2], dx * b4.z);
                acc = fmaf(h[4*k+2], c4.z, acc);
                h[4*k+3] = fmaf(EXP2F(dlt * A2[4*k+3]), h[4*k+3], dx * b4.w);
                acc = fmaf(h[4*k+3], c4.w, acc);
            }
            __builtin_nontemporal_store(acc, &yp[(long)t * ED]);   // y never re-read
        }
        #pragma unroll
        for (int j = 0; j < 4; ++j) { da[j] = dn[j]; xa[j] = xn[j]; }
    }
}

// ---------------- fallback (tiny workspace): fully sequential ----------------
__global__ __launch_bounds__(EDG) void ssm_fallback(
    const float* __restrict__ x, const float* __restrict__ dl,
    const float* __restrict__ A, const float* __restrict__ B,
    const float* __restrict__ C, const float* __restrict__ Dv,
    float* __restrict__ y)
{
    const int g = blockIdx.x, b = blockIdx.y;
    const int ed = g * EDG + threadIdx.x;

    float A2[NS];
    {
        const float4* Ap = reinterpret_cast<const float4*>(A + (long)ed * NS);
        #pragma unroll
        for (int k = 0; k < 4; ++k) {
            float4 a4 = Ap[k];
            A2[4*k+0] = a4.x * LOG2E; A2[4*k+1] = a4.y * LOG2E;
            A2[4*k+2] = a4.z * LOG2E; A2[4*k+3] = a4.w * LOG2E;
        }
    }
    float h[NS];
    #pragma unroll
    for (int n = 0; n < NS; ++n) h[n] = 0.f;
    const float dvec = Dv[ed];

    for (int t = 0; t < SEQ; ++t) {
        const long tb = (long)b * SEQ + t;
        float dlt = dl[tb * ED + ed];
        float xv  = x[tb * ED + ed];
        float dx = dlt * xv;
        float acc = dvec * xv;
        const float4* Bp = reinterpret_cast<const float4*>(B + tb * NS);
        const float4* Cp = reinterpret_cast<const float4*>(C + tb * NS);
        #pragma unroll
        for (int k = 0; k < 4; ++k) {
            float4 b4 = Bp[k];
            float4 c4 = Cp[k];
            h[4*k+0] = fmaf(EXP2F(dlt * A2[4*k+0]), h[4*k+0], dx * b4.x);
            acc = fmaf(h[4*k+0], c4.x, acc);
            h[4*k+1] = fmaf(EXP2F(dlt * A2[4*k+1]), h[4*k+1], dx * b4.y);
            acc = fmaf(h[4*k+1], c4.y, acc);
            h[4*k+2] = fmaf(EXP2F(dlt * A2[4*k+2]), h[4*k+2], dx * b4.z);
            acc = fmaf(h[4*k+2], c4.z, acc);
            h[4*k+3] = fmaf(EXP2F(dlt * A2[4*k+3]), h[4*k+3], dx * b4.w);
            acc = fmaf(h[4*k+3], c4.w, acc);
        }
        y[tb * ED + ed] = acc;
    }
}

extern "C" void kernel_launch(void* const* d_in, const int* in_sizes, int n_in,
                              void* d_out, int out_size, void* d_ws, size_t ws_size,
                              hipStream_t stream) {
    const float* x  = (const float*)d_in[0];
    const float* dl = (const float*)d_in[1];
    const float* A  = (const float*)d_in[2];
    const float* B  = (const float*)d_in[3];
    const float* C  = (const float*)d_in[4];
    const float* Dv = (const float*)d_in[5];
    float* y = (float*)d_out;

    const size_t qElems = (size_t)NC * BATCH * ED * NS;   // 2M floats
    const size_t dElems = (size_t)NC * BATCH * ED;        // 128K floats
    const size_t need = (2 * qElems + dElems) * sizeof(float);  // ~16.5 MB

    if (ws_size >= need) {
        float* Q     = (float*)d_ws;
        float* Hprev = Q + qElems;
        float* Dsum  = Hprev + qElems;
        ssm_pass1<<<dim3(NC, NEG, BATCH), EDG, 0, stream>>>(x, dl, A, B, Q, Dsum);
        ssm_pass2<<<(BATCH * ED * NS) / 128, 128, 0, stream>>>(A, Q, Dsum, Hprev);
        ssm_pass3<<<dim3(NC, NEG, BATCH), EDG, 0, stream>>>(x, dl, A, B, C, Dv, Hprev, y);
    } else {
        ssm_fallback<<<dim3(NEG, BATCH), EDG, 0, stream>>>(x, dl, A, B, C, Dv, y);
    }
}